// Round 1
// baseline (743.201 us; speedup 1.0000x reference)
//
#include <hip/hip_runtime.h>

// ---------------- problem constants ----------------
#define M_DIM 2048        // tlen*batch
#define K_DIM 1024        // input_size
#define N_DIM 32000       // vocab
#define CVOCAB 120
#define AGENDA 100
#define SLEN 400
#define CTX 300
#define BATCH 16
#define OUT_STRIDE 32120  // vocab + cvocab
#define PAD_IDX 1

typedef float f32x4_t  __attribute__((ext_vector_type(4)));
typedef __bf16 bf16x8_t __attribute__((ext_vector_type(8)));
typedef unsigned short u16x8_t __attribute__((ext_vector_type(8)));
typedef unsigned short u16x4_t __attribute__((ext_vector_type(4)));

// RNE fp32 -> bf16 (values are all normal, no NaN handling needed)
__device__ __forceinline__ unsigned short f2bf(float f) {
    union { float f; unsigned int u; } c; c.f = f;
    unsigned int u = c.u;
    u += 0x7FFFu + ((u >> 16) & 1u);
    return (unsigned short)(u >> 16);
}

// async 16B global->LDS (dest = wave-uniform base + lane*16)
__device__ __forceinline__ void async_copy16(const void* gsrc, void* ldst) {
    __builtin_amdgcn_global_load_lds(
        (__attribute__((address_space(1))) unsigned int*)(gsrc),
        (__attribute__((address_space(3))) unsigned int*)(ldst),
        16, 0, 0);
}

// ---------------- kernel 1: fp32 -> bf16 cast of W and hidden ----------------
__global__ void cast_bf16_kernel(const float4* __restrict__ W, const float4* __restrict__ H,
                                 unsigned short* __restrict__ Wb, unsigned short* __restrict__ Hb) {
    const size_t NW4 = (size_t)N_DIM * K_DIM / 4;   // 8,192,000
    const size_t NH4 = (size_t)M_DIM * K_DIM / 4;   // 524,288
    size_t idx = (size_t)blockIdx.x * 256 + threadIdx.x;
    float4 v; unsigned short* dst;
    if (idx < NW4)            { v = W[idx];        dst = Wb + idx * 4; }
    else if (idx < NW4 + NH4) { v = H[idx - NW4];  dst = Hb + (idx - NW4) * 4; }
    else return;
    u16x4_t o;
    o[0] = f2bf(v.x); o[1] = f2bf(v.y); o[2] = f2bf(v.z); o[3] = f2bf(v.w);
    *(u16x4_t*)dst = o;
}

// ---------------- kernel 2: p_copy = sigmoid(hidden @ W_copy^T + b_copy) ----------------
__global__ void pcopy_kernel(const float* __restrict__ hidden, const float* __restrict__ Wc,
                             const float* __restrict__ bc, float* __restrict__ pcopy,
                             float* __restrict__ out_tail) {
    int row  = blockIdx.x * 4 + (threadIdx.x >> 6);  // 4 waves/block, 1 row/wave
    int lane = threadIdx.x & 63;
    const float4* h = (const float4*)(hidden + (size_t)row * K_DIM);
    const float4* w = (const float4*)Wc;
    float s = 0.f;
    #pragma unroll
    for (int i = 0; i < 4; ++i) {
        float4 a = h[lane + 64 * i];
        float4 b = w[lane + 64 * i];
        s += a.x * b.x + a.y * b.y + a.z * b.z + a.w * b.w;
    }
    #pragma unroll
    for (int m = 1; m < 64; m <<= 1) s += __shfl_xor(s, m);
    if (lane == 0) {
        float p = 1.0f / (1.0f + __expf(-(s + bc[0])));
        pcopy[row]    = p;
        out_tail[row] = p;
    }
}

// ---------------- kernel 3: GEMM + exp + row-sum ----------------
// C[m,n] = sum_k A[m,k]*B[n,k]; writes exp(C+bias) (0 at PAD) to out, atomicAdds row sums.
__global__ __launch_bounds__(256, 2) void gemm_exp_kernel(
    const unsigned short* __restrict__ A,   // M x K bf16
    const unsigned short* __restrict__ B,   // N x K bf16
    const float* __restrict__ bias,         // N
    float* __restrict__ out,                // row stride OUT_STRIDE
    float* __restrict__ rowsum)             // M (pre-zeroed)
{
    __shared__ unsigned short sA[128 * 64];
    __shared__ unsigned short sB[128 * 64];

    const int tid   = threadIdx.x;
    const int lane  = tid & 63;
    const int q     = lane >> 4;
    const int lr    = lane & 15;
    const int wv    = tid >> 6;
    const int waveM = wv >> 1;       // 0..1 -> 64-row half
    const int waveN = wv & 1;        // 0..1 -> 64-col half
    const int rowBase = blockIdx.y * 128;
    const int colBase = blockIdx.x * 128;

    f32x4_t acc[4][4] = {};

    // Staging: tile = 128 rows x 64 k (128B/row = 8 chunks of 16B).
    // LDS chunk position p = row*8 + (j ^ (row&7))  (XOR swizzle kills bank conflicts)
    const unsigned short* aSrc[4];
    const unsigned short* bSrc[4];
    unsigned short* aDst[4];
    unsigned short* bDst[4];
    #pragma unroll
    for (int it = 0; it < 4; ++it) {
        int p = it * 256 + tid;
        int m = p >> 3;
        int j = (p & 7) ^ (m & 7);
        aSrc[it] = A + (size_t)(rowBase + m) * K_DIM + j * 8;
        bSrc[it] = B + (size_t)(colBase + m) * K_DIM + j * 8;
        aDst[it] = sA + (it * 256 + (tid & ~63)) * 8;
        bDst[it] = sB + (it * 256 + (tid & ~63)) * 8;
    }

    for (int k0 = 0; k0 < K_DIM; k0 += 64) {
        #pragma unroll
        for (int it = 0; it < 4; ++it) async_copy16(aSrc[it] + k0, aDst[it]);
        #pragma unroll
        for (int it = 0; it < 4; ++it) async_copy16(bSrc[it] + k0, bDst[it]);
        __syncthreads();   // compiler emits vmcnt(0) drain before barrier

        #pragma unroll
        for (int s = 0; s < 2; ++s) {   // two 16x16x32 K-steps
            u16x8_t af[4], bfr[4];
            #pragma unroll
            for (int r = 0; r < 4; ++r) {
                int m  = waveM * 64 + r * 16 + lr;
                int ch = (s * 4 + q) ^ (m & 7);
                af[r] = *(const u16x8_t*)(sA + m * 64 + ch * 8);
            }
            #pragma unroll
            for (int c = 0; c < 4; ++c) {
                int n  = waveN * 64 + c * 16 + lr;
                int ch = (s * 4 + q) ^ (n & 7);
                bfr[c] = *(const u16x8_t*)(sB + n * 64 + ch * 8);
            }
            #pragma unroll
            for (int r = 0; r < 4; ++r)
                #pragma unroll
                for (int c = 0; c < 4; ++c)
                    acc[r][c] = __builtin_amdgcn_mfma_f32_16x16x32_bf16(
                        __builtin_bit_cast(bf16x8_t, af[r]),
                        __builtin_bit_cast(bf16x8_t, bfr[c]),
                        acc[r][c], 0, 0, 0);
        }
        __syncthreads();
    }

    // epilogue: C/D layout col=lane&15 (vocab n), row=quad*4+reg (token m)
    float bb[4];
    #pragma unroll
    for (int c = 0; c < 4; ++c) bb[c] = bias[colBase + waveN * 64 + c * 16 + lr];

    #pragma unroll
    for (int r = 0; r < 4; ++r) {
        float rsum[4] = {0.f, 0.f, 0.f, 0.f};
        #pragma unroll
        for (int c = 0; c < 4; ++c) {
            int gcol = colBase + waveN * 64 + c * 16 + lr;
            #pragma unroll
            for (int d = 0; d < 4; ++d) {
                int grow = rowBase + waveM * 64 + r * 16 + q * 4 + d;
                float e = (gcol == PAD_IDX) ? 0.0f : __expf(acc[r][c][d] + bb[c]);
                out[(size_t)grow * OUT_STRIDE + gcol] = e;
                rsum[d] += e;
            }
        }
        #pragma unroll
        for (int d = 0; d < 4; ++d) {
            float v = rsum[d];
            v += __shfl_xor(v, 1);
            v += __shfl_xor(v, 2);
            v += __shfl_xor(v, 4);
            v += __shfl_xor(v, 8);
            if (lr == 0) {
                int grow = rowBase + waveM * 64 + r * 16 + q * 4 + d;
                atomicAdd(&rowsum[grow], v);
            }
        }
    }
}

// ---------------- kernel 4: scale out_prob rows by (1-p_copy)/rowsum ----------------
__global__ void normalize_kernel(float* __restrict__ out, const float* __restrict__ rowsum,
                                 const float* __restrict__ pcopy) {
    int n = blockIdx.y;
    int j = blockIdx.x * 256 + threadIdx.x;   // float4 index within row, < 8000
    if (j >= N_DIM / 4) return;
    float scale = (1.0f - pcopy[n]) / rowsum[n];
    float4* p = (float4*)(out + (size_t)n * OUT_STRIDE) + j;
    float4 v = *p;
    v.x *= scale; v.y *= scale; v.z *= scale; v.w *= scale;
    *p = v;
}

// ---------------- kernel 5: copy_prob = einsum('tba,abv->tbv') ----------------
__global__ void copy_prob_kernel(const float* __restrict__ attn, const float* __restrict__ src_map,
                                 const float* __restrict__ pcopy, float* __restrict__ out) {
    int n = blockIdx.x;          // row (t*BATCH + b)
    int t = threadIdx.x;         // 128 threads
    int bidx = n & (BATCH - 1);
    __shared__ float ma[AGENDA];
    float pc = pcopy[n];
    if (t < AGENDA) ma[t] = attn[(size_t)n * SLEN + CTX + t] * pc;
    __syncthreads();
    if (t < CVOCAB) {
        float s = 0.f;
        #pragma unroll 4
        for (int a = 0; a < AGENDA; ++a)
            s += ma[a] * src_map[(size_t)(a * BATCH + bidx) * CVOCAB + t];
        out[(size_t)n * OUT_STRIDE + N_DIM + t] = s;
    }
}

// ---------------- launch ----------------
extern "C" void kernel_launch(void* const* d_in, const int* in_sizes, int n_in,
                              void* d_out, int out_size, void* d_ws, size_t ws_size,
                              hipStream_t stream) {
    const float* hidden  = (const float*)d_in[0];
    const float* attn    = (const float*)d_in[1];
    const float* src_map = (const float*)d_in[2];
    const float* W       = (const float*)d_in[3];
    const float* b       = (const float*)d_in[4];
    const float* W_copy  = (const float*)d_in[5];
    const float* b_copy  = (const float*)d_in[6];
    float* out = (float*)d_out;

    // workspace layout
    char* ws = (char*)d_ws;
    unsigned short* Wb = (unsigned short*)ws;                               // 65,536,000 B
    unsigned short* Hb = (unsigned short*)(ws + 65536000);                  //  4,194,304 B
    float* rowsum      = (float*)(ws + 65536000 + 4194304);                 //      8,192 B
    float* pcopy       = (float*)(ws + 65536000 + 4194304 + 8192);          //      8,192 B

    float* out_tail = out + (size_t)M_DIM * OUT_STRIDE;  // p_copy output

    // 1. cast W + hidden to bf16
    {
        size_t total4 = (size_t)N_DIM * K_DIM / 4 + (size_t)M_DIM * K_DIM / 4;
        int blocks = (int)((total4 + 255) / 256);
        cast_bf16_kernel<<<blocks, 256, 0, stream>>>((const float4*)W, (const float4*)hidden, Wb, Hb);
    }
    // 2. zero row sums (ws is poisoned every call)
    hipMemsetAsync(rowsum, 0, M_DIM * sizeof(float), stream);
    // 3. p_copy
    pcopy_kernel<<<M_DIM / 4, 256, 0, stream>>>(hidden, W_copy, b_copy, pcopy, out_tail);
    // 4. GEMM + exp + rowsum
    {
        dim3 grid(N_DIM / 128, M_DIM / 128);  // 250 x 16
        gemm_exp_kernel<<<grid, 256, 0, stream>>>(Hb, Wb, b, out, rowsum);
    }
    // 5. normalize out_prob
    {
        dim3 grid((N_DIM / 4 + 255) / 256, M_DIM);  // 32 x 2048
        normalize_kernel<<<grid, 256, 0, stream>>>(out, rowsum, pcopy);
    }
    // 6. copy_prob
    copy_prob_kernel<<<M_DIM, 128, 0, stream>>>(attn, src_map, pcopy, out);
}

// Round 2
// 623.421 us; speedup vs baseline: 1.1921x; 1.1921x over previous
//
#include <hip/hip_runtime.h>

// ---------------- problem constants ----------------
#define M_DIM 2048        // tlen*batch
#define K_DIM 1024        // input_size
#define N_DIM 32000       // vocab
#define CVOCAB 120
#define AGENDA 100
#define SLEN 400
#define CTX 300
#define BATCH 16
#define OUT_STRIDE 32120  // vocab + cvocab
#define PAD_IDX 1

#define TM 256            // GEMM tile M
#define TN 256            // GEMM tile N
#define BK 64             // GEMM K-step

typedef float f32x4_t  __attribute__((ext_vector_type(4)));
typedef __bf16 bf16x8_t __attribute__((ext_vector_type(8)));
typedef unsigned short u16x8_t __attribute__((ext_vector_type(8)));
typedef unsigned short u16x4_t __attribute__((ext_vector_type(4)));

// RNE fp32 -> bf16 (values are all normal, no NaN handling needed)
__device__ __forceinline__ unsigned short f2bf(float f) {
    union { float f; unsigned int u; } c; c.f = f;
    unsigned int u = c.u;
    u += 0x7FFFu + ((u >> 16) & 1u);
    return (unsigned short)(u >> 16);
}

// async 16B global->LDS (dest = wave-uniform base + lane*16)
__device__ __forceinline__ void async_copy16(const void* gsrc, void* ldst) {
    __builtin_amdgcn_global_load_lds(
        (__attribute__((address_space(1))) unsigned int*)(gsrc),
        (__attribute__((address_space(3))) unsigned int*)(ldst),
        16, 0, 0);
}

// ---------------- kernel 1: fp32 -> bf16 cast of W and hidden ----------------
__global__ void cast_bf16_kernel(const float4* __restrict__ W, const float4* __restrict__ H,
                                 unsigned short* __restrict__ Wb, unsigned short* __restrict__ Hb) {
    const size_t NW4 = (size_t)N_DIM * K_DIM / 4;   // 8,192,000
    const size_t NH4 = (size_t)M_DIM * K_DIM / 4;   // 524,288
    size_t idx = (size_t)blockIdx.x * 256 + threadIdx.x;
    float4 v; unsigned short* dst;
    if (idx < NW4)            { v = W[idx];        dst = Wb + idx * 4; }
    else if (idx < NW4 + NH4) { v = H[idx - NW4];  dst = Hb + (idx - NW4) * 4; }
    else return;
    u16x4_t o;
    o[0] = f2bf(v.x); o[1] = f2bf(v.y); o[2] = f2bf(v.z); o[3] = f2bf(v.w);
    *(u16x4_t*)dst = o;
}

// ---------------- kernel 2: p_copy = sigmoid(hidden @ W_copy^T + b_copy) ----------------
__global__ void pcopy_kernel(const float* __restrict__ hidden, const float* __restrict__ Wc,
                             const float* __restrict__ bc, float* __restrict__ pcopy) {
    int row  = blockIdx.x * 4 + (threadIdx.x >> 6);  // 4 waves/block, 1 row/wave
    int lane = threadIdx.x & 63;
    const float4* h = (const float4*)(hidden + (size_t)row * K_DIM);
    const float4* w = (const float4*)Wc;
    float s = 0.f;
    #pragma unroll
    for (int i = 0; i < 4; ++i) {
        float4 a = h[lane + 64 * i];
        float4 b = w[lane + 64 * i];
        s += a.x * b.x + a.y * b.y + a.z * b.z + a.w * b.w;
    }
    #pragma unroll
    for (int m = 1; m < 64; m <<= 1) s += __shfl_xor(s, m);
    if (lane == 0) {
        float p = 1.0f / (1.0f + __expf(-(s + bc[0])));
        pcopy[row] = p;
    }
}

// ---------------- kernel 3: GEMM + exp + row-sum (256x256 tile, 16 waves) ----------------
// C[m,n] = sum_k A[m,k]*B[n,k]; writes exp(C+bias) (0 at PAD) to out, accumulates row sums.
__global__ __launch_bounds__(1024, 4) void gemm_exp_kernel(
    const unsigned short* __restrict__ A,   // M x K bf16
    const unsigned short* __restrict__ B,   // N x K bf16
    const float* __restrict__ bias,         // N
    float* __restrict__ out,                // row stride OUT_STRIDE
    float* __restrict__ rowsum)             // M (pre-zeroed)
{
    __shared__ unsigned short sA[TM * BK];  // 32 KB
    __shared__ unsigned short sB[TN * BK];  // 32 KB
    __shared__ float sRow[TM];              // 1 KB

    const int tid   = threadIdx.x;          // 0..1023
    const int lane  = tid & 63;
    const int q     = lane >> 4;
    const int lr    = lane & 15;
    const int wv    = tid >> 6;             // 0..15
    const int waveM = wv >> 2;              // 0..3 -> 64-row quarter
    const int waveN = wv & 3;               // 0..3 -> 64-col quarter
    const int rowBase = blockIdx.x * TM;    // M fastest-varying: concurrent blocks share B tile
    const int colBase = blockIdx.y * TN;

    f32x4_t acc[4][4] = {};

    if (tid < TM) sRow[tid] = 0.0f;

    // Staging: tile = 256 rows x 64 k (128B/row = 8 chunks of 16B) = 2048 chunks, 2/thread.
    // LDS chunk position p = row*8 + (j ^ (row&7))  (XOR swizzle: conflict-free reads)
    const unsigned short* aSrc[2];
    const unsigned short* bSrc[2];
    unsigned short* aDst[2];
    unsigned short* bDst[2];
    #pragma unroll
    for (int it = 0; it < 2; ++it) {
        int p = it * 1024 + tid;
        int m = p >> 3;
        int j = (p & 7) ^ (m & 7);
        aSrc[it] = A + (size_t)(rowBase + m) * K_DIM + j * 8;
        bSrc[it] = B + (size_t)(colBase + m) * K_DIM + j * 8;
        aDst[it] = sA + (it * 1024 + (tid & ~63)) * 8;
        bDst[it] = sB + (it * 1024 + (tid & ~63)) * 8;
    }

    for (int k0 = 0; k0 < K_DIM; k0 += BK) {
        #pragma unroll
        for (int it = 0; it < 2; ++it) async_copy16(aSrc[it] + k0, aDst[it]);
        #pragma unroll
        for (int it = 0; it < 2; ++it) async_copy16(bSrc[it] + k0, bDst[it]);
        __syncthreads();

        #pragma unroll
        for (int s = 0; s < 2; ++s) {   // two 16x16x32 K-steps
            u16x8_t af[4], bfr[4];
            #pragma unroll
            for (int r = 0; r < 4; ++r) {
                int m  = waveM * 64 + r * 16 + lr;
                int ch = (s * 4 + q) ^ (m & 7);
                af[r] = *(const u16x8_t*)(sA + m * BK + ch * 8);
            }
            #pragma unroll
            for (int c = 0; c < 4; ++c) {
                int n  = waveN * 64 + c * 16 + lr;
                int ch = (s * 4 + q) ^ (n & 7);
                bfr[c] = *(const u16x8_t*)(sB + n * BK + ch * 8);
            }
            #pragma unroll
            for (int r = 0; r < 4; ++r)
                #pragma unroll
                for (int c = 0; c < 4; ++c)
                    acc[r][c] = __builtin_amdgcn_mfma_f32_16x16x32_bf16(
                        __builtin_bit_cast(bf16x8_t, af[r]),
                        __builtin_bit_cast(bf16x8_t, bfr[c]),
                        acc[r][c], 0, 0, 0);
        }
        __syncthreads();
    }

    // epilogue: C/D layout col=lane&15 (vocab n), row=quad*4+reg (token m)
    float bb[4];
    #pragma unroll
    for (int c = 0; c < 4; ++c) bb[c] = bias[colBase + waveN * 64 + c * 16 + lr];

    #pragma unroll
    for (int r = 0; r < 4; ++r) {
        float rsum[4] = {0.f, 0.f, 0.f, 0.f};
        #pragma unroll
        for (int c = 0; c < 4; ++c) {
            int gcol = colBase + waveN * 64 + c * 16 + lr;
            #pragma unroll
            for (int d = 0; d < 4; ++d) {
                int grow = rowBase + waveM * 64 + r * 16 + q * 4 + d;
                float e = (gcol == PAD_IDX) ? 0.0f : __expf(acc[r][c][d] + bb[c]);
                out[(size_t)grow * OUT_STRIDE + gcol] = e;
                rsum[d] += e;
            }
        }
        #pragma unroll
        for (int d = 0; d < 4; ++d) {
            float v = rsum[d];
            v += __shfl_xor(v, 1);
            v += __shfl_xor(v, 2);
            v += __shfl_xor(v, 4);
            v += __shfl_xor(v, 8);
            if (lr == 0) {
                int lrow = waveM * 64 + r * 16 + q * 4 + d;
                atomicAdd(&sRow[lrow], v);   // LDS atomic: 4x fewer global atomics
            }
        }
    }
    __syncthreads();
    if (tid < TM) atomicAdd(&rowsum[rowBase + tid], sRow[tid]);
}

// ---------------- kernel 4: fused normalize + copy_prob + p_copy tail ----------------
__global__ void finalize_kernel(float* __restrict__ out, const float* __restrict__ rowsum,
                                const float* __restrict__ pcopy, const float* __restrict__ attn,
                                const float* __restrict__ src_map, float* __restrict__ out_tail) {
    int n   = blockIdx.x;        // row (t*BATCH + b)
    int tid = threadIdx.x;       // 256 threads
    int bidx = n & (BATCH - 1);
    float p = pcopy[n];
    float scale = (1.0f - p) / rowsum[n];

    __shared__ float ma[AGENDA];
    if (tid < AGENDA) ma[tid] = attn[(size_t)n * SLEN + CTX + tid] * p;

    // scale vocab portion (8000 float4s per row)
    float4* row4 = (float4*)(out + (size_t)n * OUT_STRIDE);
    for (int j = tid; j < N_DIM / 4; j += 256) {
        float4 v = row4[j];
        v.x *= scale; v.y *= scale; v.z *= scale; v.w *= scale;
        row4[j] = v;
    }
    __syncthreads();

    if (tid < CVOCAB) {
        float s = 0.f;
        #pragma unroll 4
        for (int a = 0; a < AGENDA; ++a)
            s += ma[a] * src_map[(size_t)(a * BATCH + bidx) * CVOCAB + tid];
        out[(size_t)n * OUT_STRIDE + N_DIM + tid] = s;
    }
    if (tid == 0) out_tail[n] = p;
}

// ---------------- launch ----------------
extern "C" void kernel_launch(void* const* d_in, const int* in_sizes, int n_in,
                              void* d_out, int out_size, void* d_ws, size_t ws_size,
                              hipStream_t stream) {
    const float* hidden  = (const float*)d_in[0];
    const float* attn    = (const float*)d_in[1];
    const float* src_map = (const float*)d_in[2];
    const float* W       = (const float*)d_in[3];
    const float* b       = (const float*)d_in[4];
    const float* W_copy  = (const float*)d_in[5];
    const float* b_copy  = (const float*)d_in[6];
    float* out = (float*)d_out;

    // workspace layout
    char* ws = (char*)d_ws;
    unsigned short* Wb = (unsigned short*)ws;                               // 65,536,000 B
    unsigned short* Hb = (unsigned short*)(ws + 65536000);                  //  4,194,304 B
    float* rowsum      = (float*)(ws + 65536000 + 4194304);                 //      8,192 B
    float* pcopy       = (float*)(ws + 65536000 + 4194304 + 8192);          //      8,192 B

    float* out_tail = out + (size_t)M_DIM * OUT_STRIDE;  // p_copy output

    // 1. cast W + hidden to bf16
    {
        size_t total4 = (size_t)N_DIM * K_DIM / 4 + (size_t)M_DIM * K_DIM / 4;
        int blocks = (int)((total4 + 255) / 256);
        cast_bf16_kernel<<<blocks, 256, 0, stream>>>((const float4*)W, (const float4*)hidden, Wb, Hb);
    }
    // 2. zero row sums (ws is poisoned every call)
    hipMemsetAsync(rowsum, 0, M_DIM * sizeof(float), stream);
    // 3. p_copy
    pcopy_kernel<<<M_DIM / 4, 256, 0, stream>>>(hidden, W_copy, b_copy, pcopy);
    // 4. GEMM + exp + rowsum   (grid: M-tiles fastest so concurrent blocks share B tile)
    {
        dim3 grid(M_DIM / TM, N_DIM / TN);  // 8 x 125
        gemm_exp_kernel<<<grid, 1024, 0, stream>>>(Hb, Wb, b, out, rowsum);
    }
    // 5. fused normalize + copy_prob + p_copy tail
    finalize_kernel<<<M_DIM, 256, 0, stream>>>(out, rowsum, pcopy, attn, src_map, out_tail);
}